// Round 7
// baseline (373.208 us; speedup 1.0000x reference)
//
#include <hip/hip_runtime.h>

#define N_NODES 50000
#define N_EDGES 300000
#define N_TOT   350000   // edges + self-loops
#define D       256
#define MPAD    50048    // N_NODES padded to multiple of 128 for GEMM
#define SCAN_B  196      // ceil(50000/256)

typedef __attribute__((ext_vector_type(8))) short bf16x8;
typedef __attribute__((ext_vector_type(4))) float f32x4;
typedef __attribute__((ext_vector_type(8))) unsigned short u16x8;

__device__ __forceinline__ float bf2f(unsigned short b) {
    union { unsigned u; float f; } v; v.u = ((unsigned)b) << 16; return v.f;
}
__device__ __forceinline__ unsigned short f2bf(float f) {
    union { float f; unsigned u; } v; v.f = f;
    unsigned u = v.u;
    unsigned r = (u + 0x7FFFu + ((u >> 16) & 1u)) >> 16;   // round-nearest-even
    return (unsigned short)r;
}
__device__ __forceinline__ void g2lds16(const unsigned short* g, unsigned short* l) {
    __builtin_amdgcn_global_load_lds(
        (const __attribute__((address_space(1))) void*)g,
        (__attribute__((address_space(3))) void*)l, 16, 0, 0);
}

// ---- k1: hist + W-transpose + embed, all independent, grid = MPAD/8 = 6256 ----
__global__ __launch_bounds__(256) void k1_kernel(
        const float* __restrict__ x, const int* __restrict__ ei,
        const float* __restrict__ We, const float* __restrict__ be,
        const float* __restrict__ W1, const float* __restrict__ W2,
        int* __restrict__ cnt,
        unsigned short* __restrict__ Wt1, unsigned short* __restrict__ Wt2,
        unsigned short* __restrict__ hA) {
    int t = threadIdx.x, b = blockIdx.x;
    int tid = b * 256 + t;

    // histogram over dst (cnt pre-zeroed by memset)
    if (tid < N_TOT) {
        int dst = (tid < N_EDGES) ? ei[N_EDGES + tid] : (tid - N_EDGES);
        atomicAdd(&cnt[dst], 1);
    }
    // transpose + cast weights (first 512 blocks, 1 elem/thread)
    if (tid < 2 * D * D) {
        int wsel = tid >> 16, rem = tid & 65535;
        int tt = rem >> 8, bb = rem & 255;             // coalesced over bb
        const float* W = wsel ? W2 : W1;
        unsigned short* Wt = wsel ? Wt2 : Wt1;
        Wt[bb * D + tt] = f2bf(W[tt * D + bb]);
    }
    // embed: block b -> nodes b*8 .. b*8+7 (pad rows get 0)
    float w[11];
    #pragma unroll
    for (int k = 0; k < 11; ++k) w[k] = We[k * D + t];
    float bb = be[t];
    #pragma unroll
    for (int ni = 0; ni < 8; ++ni) {
        int node = b * 8 + ni;
        float acc = 0.f;
        if (node < N_NODES) {
            acc = bb;
            #pragma unroll
            for (int k = 0; k < 11; ++k) acc += x[node * 11 + k] * w[k];
            acc = fmaxf(acc, 0.f);
        }
        hA[(size_t)node * D + t] = f2bf(acc);
    }
}

// ---- k2: deg_inv_sqrt + per-256-chunk inclusive scan + last-block bsum scan ----
__global__ __launch_bounds__(256) void k2_kernel(const int* __restrict__ cnt,
                                                 float* __restrict__ dis,
                                                 int* __restrict__ locs,
                                                 int* __restrict__ bsum,
                                                 int* __restrict__ done) {
    __shared__ int ws[4];
    __shared__ int amLast;
    int t = threadIdx.x, lane = t & 63, wv = t >> 6;
    int i = blockIdx.x * 256 + t;
    int v = (i < N_NODES) ? cnt[i] : 0;
    if (i < N_NODES) dis[i] = rsqrtf((float)v);        // deg >= 1 (self-loop)
    int s = v;
    #pragma unroll
    for (int d = 1; d < 64; d <<= 1) {
        int u = __shfl_up(s, d, 64);
        if (lane >= d) s += u;
    }
    if (lane == 63) ws[wv] = s;
    __syncthreads();
    int off = 0;
    #pragma unroll
    for (int k = 0; k < 4; ++k) if (k < wv) off += ws[k];
    s += off;
    if (i < N_NODES) locs[i] = s;                      // inclusive local scan

    // publish chunk total + elect last block (release: store, fence, atomic)
    if (t == 255) {
        bsum[blockIdx.x] = s;
        __threadfence();
        amLast = (atomicAdd(done, 1) == SCAN_B - 1);
    }
    __syncthreads();
    if (amLast) {
        __threadfence();                               // acquire side
        int vv = 0;
        if (t < SCAN_B)
            vv = __hip_atomic_load(&bsum[t], __ATOMIC_RELAXED, __HIP_MEMORY_SCOPE_AGENT);
        int ss = vv;
        #pragma unroll
        for (int d = 1; d < 64; d <<= 1) {
            int u = __shfl_up(ss, d, 64);
            if (lane >= d) ss += u;
        }
        __syncthreads();                               // ws reuse
        if (lane == 63) ws[wv] = ss;
        __syncthreads();
        int off2 = 0;
        #pragma unroll
        for (int k = 0; k < 4; ++k) if (k < wv) off2 += ws[k];
        ss += off2;
        if (t < SCAN_B) bsum[t] = ss - vv;             // exclusive block offsets
    }
}

// ---- k3: rowptr materialization + CSR fill (esrc only; norm is factored out) ----
__global__ void k3_kernel(const int* __restrict__ ei, const int* __restrict__ locs,
                          const int* __restrict__ bsum, int* __restrict__ fc,
                          int* __restrict__ rowptr, int* __restrict__ esrc) {
    int tid = blockIdx.x * 256 + threadIdx.x;
    if (tid == 0) rowptr[0] = 0;
    if (tid < N_NODES)
        rowptr[tid + 1] = locs[tid] + bsum[tid >> 8];
    if (tid < N_TOT) {
        int src, dst;
        if (tid < N_EDGES) { src = ei[tid]; dst = ei[N_EDGES + tid]; }
        else               { src = dst = tid - N_EDGES; }
        int base = bsum[dst >> 8] + ((dst & 255) ? locs[dst - 1] : 0);
        int pos = base + atomicAdd(&fc[dst], 1);
        esrc[pos] = src;
    }
}

// ---- GEMM (m97-style): C[MPAD,256] = A @ W, W as Wt[n][k]; 128x128 tile, BK=32 ----
__global__ __launch_bounds__(256) void gemm_kernel(const unsigned short* __restrict__ A,
                                                   const unsigned short* __restrict__ Bt,
                                                   unsigned short* __restrict__ C) {
    __shared__ unsigned short lA[128 * 32];
    __shared__ unsigned short lB[128 * 32];
    int t = threadIdx.x;
    int wv = t >> 6, lane = t & 63;
    int m0 = blockIdx.x * 128;
    int n0 = blockIdx.y * 128;
    int moff = (wv & 1) * 64, noff = (wv >> 1) * 64;
    int q = lane >> 4, r = lane & 15;

    int srow = t >> 2;
    int skof = (t & 3) * 8;

    const unsigned short* Ag0 = A  + (size_t)(m0 + srow) * D + skof;
    const unsigned short* Ag1 = Ag0 + (size_t)64 * D;
    const unsigned short* Bg0 = Bt + (size_t)(n0 + srow) * D + skof;
    const unsigned short* Bg1 = Bg0 + (size_t)64 * D;
    unsigned short* lA0 = lA + t * 8;
    unsigned short* lA1 = lA0 + 64 * 32;
    unsigned short* lB0 = lB + t * 8;
    unsigned short* lB1 = lB0 + 64 * 32;

    f32x4 acc[4][4] = {};
    for (int kk = 0; kk < D; kk += 32) {
        __syncthreads();
        g2lds16(Ag0 + kk, lA0);
        g2lds16(Ag1 + kk, lA1);
        g2lds16(Bg0 + kk, lB0);
        g2lds16(Bg1 + kk, lB1);
        __syncthreads();
        bf16x8 a[4], b[4];
        #pragma unroll
        for (int mt = 0; mt < 4; ++mt)
            a[mt] = *(const bf16x8*)(lA + (moff + mt * 16 + r) * 32 + q * 8);
        #pragma unroll
        for (int nt = 0; nt < 4; ++nt)
            b[nt] = *(const bf16x8*)(lB + (noff + nt * 16 + r) * 32 + q * 8);
        #pragma unroll
        for (int mt = 0; mt < 4; ++mt)
            #pragma unroll
            for (int nt = 0; nt < 4; ++nt)
                acc[mt][nt] = __builtin_amdgcn_mfma_f32_16x16x32_bf16(a[mt], b[nt], acc[mt][nt], 0, 0, 0);
    }
    #pragma unroll
    for (int mt = 0; mt < 4; ++mt)
        #pragma unroll
        for (int nt = 0; nt < 4; ++nt) {
            int col  = n0 + noff + nt * 16 + r;
            int rowb = m0 + moff + mt * 16 + q * 4;
            #pragma unroll
            for (int i = 0; i < 4; ++i)
                C[(size_t)(rowb + i) * D + col] = f2bf(acc[mt][nt][i]);
        }
}

// ---- agg v3: column-sliced (8 x 32 cols), XCD-aware via blockIdx&7, factored norm.
// Wave per node; per trip 4 edges x 16 lanes x 4B (one 64B line per edge row slice).
__global__ __launch_bounds__(256) void agg_kernel(const unsigned short* __restrict__ hw,
                                                  const int* __restrict__ rowptr,
                                                  const int* __restrict__ esrc,
                                                  const float* __restrict__ dis,
                                                  const float* __restrict__ bias,
                                                  unsigned short* __restrict__ out_bf,
                                                  float* __restrict__ out_f32,
                                                  int mode) {
    int b = blockIdx.x;
    int slice = b & 7;
    int chunk = b >> 3;
    int wv = threadIdx.x >> 6, lane = threadIdx.x & 63;
    int sub = lane >> 4, cl = lane & 15;
    int colbase = slice * 32 + cl * 2;

    #pragma unroll
    for (int ni = 0; ni < 4; ++ni) {
        int node = chunk * 16 + wv * 4 + ni;
        if (node >= N_NODES) break;
        int s0 = rowptr[node], s1 = rowptr[node + 1];
        float a0 = 0.f, a1 = 0.f;
        for (int base = s0; base < s1; base += 64) {   // one trip in practice
            int ec = s1 - base; if (ec > 64) ec = 64;
            int srcl = 0; float dsl = 0.f;
            if (lane < ec) { srcl = esrc[base + lane]; dsl = dis[srcl]; }
            int it = (ec + 3) >> 2;
            for (int i = 0; i < it; ++i) {
                int   e  = 4 * i + sub;                // e<64; lanes>=ec hold dsl=0
                int   s  = __shfl(srcl, e, 64);
                float dv = __shfl(dsl, e, 64);
                unsigned hv = *(const unsigned*)(hw + (size_t)s * D + colbase);
                a0 += dv * bf2f((unsigned short)(hv & 0xffffu));
                a1 += dv * bf2f((unsigned short)(hv >> 16));
            }
        }
        a0 += __shfl_xor(a0, 16, 64); a0 += __shfl_xor(a0, 32, 64);
        a1 += __shfl_xor(a1, 16, 64); a1 += __shfl_xor(a1, 32, 64);
        if (lane < 16) {
            float dn = dis[node];
            float2 bv = *(const float2*)(bias + colbase);
            float v0 = dn * a0 + bv.x;
            float v1 = dn * a1 + bv.y;
            if (mode) {
                v0 = fmaxf(v0, 0.f); v1 = fmaxf(v1, 0.f);
                unsigned pv = (unsigned)f2bf(v0) | ((unsigned)f2bf(v1) << 16);
                *(unsigned*)(out_bf + (size_t)node * D + colbase) = pv;
            } else {
                float2 o = { v0, v1 };
                *(float2*)(out_f32 + (size_t)node * D + colbase) = o;
            }
        }
    }
}

extern "C" void kernel_launch(void* const* d_in, const int* in_sizes, int n_in,
                              void* d_out, int out_size, void* d_ws, size_t ws_size,
                              hipStream_t stream) {
    const float* x  = (const float*)d_in[0];
    const int*   ei = (const int*)d_in[1];
    const float* We = (const float*)d_in[2];
    const float* be = (const float*)d_in[3];
    const float* W1 = (const float*)d_in[4];
    const float* b1 = (const float*)d_in[5];
    const float* W2 = (const float*)d_in[6];
    const float* b2 = (const float*)d_in[7];
    float* out = (float*)d_out;

    char* w = (char*)d_ws;
    auto alloc = [&](size_t bytes) {
        char* p = w;
        w += (bytes + 255) & ~(size_t)255;
        return p;
    };
    // cnt, fc, done contiguous -> single memset covers all three
    int*            cnt    = (int*)alloc((size_t)N_NODES * 4);     // 200192 B
    int*            fc     = (int*)alloc((size_t)N_NODES * 4);     // 200192 B
    int*            done   = (int*)alloc(4);                       // 256 B
    size_t zero_span = (size_t)((char*)(done + 64) - (char*)cnt);  // 400640 B
    int*            rowptr = (int*)alloc((size_t)(N_NODES + 1) * 4);
    int*            locs   = (int*)alloc((size_t)N_NODES * 4);
    int*            bsum   = (int*)alloc((size_t)SCAN_B * 4);
    float*          dis    = (float*)alloc((size_t)N_NODES * 4);
    int*            esrc   = (int*)alloc((size_t)N_TOT * 4);
    unsigned short* Wt1    = (unsigned short*)alloc((size_t)D * D * 2);
    unsigned short* Wt2    = (unsigned short*)alloc((size_t)D * D * 2);
    unsigned short* hA     = (unsigned short*)alloc((size_t)MPAD * D * 2);
    unsigned short* hW     = (unsigned short*)alloc((size_t)MPAD * D * 2);

    hipMemsetAsync(cnt, 0, zero_span, stream);
    k1_kernel<<<MPAD / 8, 256, 0, stream>>>(x, ei, We, be, W1, W2, cnt, Wt1, Wt2, hA);
    k2_kernel<<<SCAN_B, 256, 0, stream>>>(cnt, dis, locs, bsum, done);
    k3_kernel<<<(N_TOT + 255) / 256, 256, 0, stream>>>(ei, locs, bsum, fc, rowptr, esrc);

    dim3 ggrid(MPAD / 128, 2);
    const int AGG_GRID = ((N_NODES + 15) / 16) * 8;    // 3125 chunks x 8 slices
    gemm_kernel<<<ggrid, 256, 0, stream>>>(hA, Wt1, hW);
    agg_kernel<<<AGG_GRID, 256, 0, stream>>>(hW, rowptr, esrc, dis, b1, hA, nullptr, 1);

    gemm_kernel<<<ggrid, 256, 0, stream>>>(hA, Wt2, hW);
    agg_kernel<<<AGG_GRID, 256, 0, stream>>>(hW, rowptr, esrc, dis, b2, nullptr, out, 0);
}

// Round 8
// 236.033 us; speedup vs baseline: 1.5812x; 1.5812x over previous
//
#include <hip/hip_runtime.h>

#define N_NODES 50000
#define N_EDGES 300000
#define N_TOT   350000   // edges + self-loops
#define D       256
#define MPAD    50048    // N_NODES padded to multiple of 128 for GEMM
#define SCAN_B  196      // ceil(50000/256)

typedef __attribute__((ext_vector_type(8))) short bf16x8;
typedef __attribute__((ext_vector_type(4))) float f32x4;
typedef __attribute__((ext_vector_type(8))) unsigned short u16x8;

__device__ __forceinline__ float bf2f(unsigned short b) {
    union { unsigned u; float f; } v; v.u = ((unsigned)b) << 16; return v.f;
}
__device__ __forceinline__ unsigned short f2bf(float f) {
    union { float f; unsigned u; } v; v.f = f;
    unsigned u = v.u;
    unsigned r = (u + 0x7FFFu + ((u >> 16) & 1u)) >> 16;   // round-nearest-even
    return (unsigned short)r;
}
__device__ __forceinline__ void g2lds16(const unsigned short* g, unsigned short* l) {
    __builtin_amdgcn_global_load_lds(
        (const __attribute__((address_space(1))) void*)g,
        (__attribute__((address_space(3))) void*)l, 16, 0, 0);
}

// ---- k1: hist + W-transpose + embed, all independent, grid = MPAD/8 = 6256 ----
__global__ __launch_bounds__(256) void k1_kernel(
        const float* __restrict__ x, const int* __restrict__ ei,
        const float* __restrict__ We, const float* __restrict__ be,
        const float* __restrict__ W1, const float* __restrict__ W2,
        int* __restrict__ cnt,
        unsigned short* __restrict__ Wt1, unsigned short* __restrict__ Wt2,
        unsigned short* __restrict__ hA) {
    int t = threadIdx.x, b = blockIdx.x;
    int tid = b * 256 + t;

    // histogram over dst (cnt pre-zeroed by memset)
    if (tid < N_TOT) {
        int dst = (tid < N_EDGES) ? ei[N_EDGES + tid] : (tid - N_EDGES);
        atomicAdd(&cnt[dst], 1);
    }
    // transpose + cast weights (first 512 blocks, 1 elem/thread)
    if (tid < 2 * D * D) {
        int wsel = tid >> 16, rem = tid & 65535;
        int tt = rem >> 8, bb = rem & 255;             // coalesced over bb
        const float* W = wsel ? W2 : W1;
        unsigned short* Wt = wsel ? Wt2 : Wt1;
        Wt[bb * D + tt] = f2bf(W[tt * D + bb]);
    }
    // embed: block b -> nodes b*8 .. b*8+7 (pad rows get 0)
    float w[11];
    #pragma unroll
    for (int k = 0; k < 11; ++k) w[k] = We[k * D + t];
    float bb = be[t];
    #pragma unroll
    for (int ni = 0; ni < 8; ++ni) {
        int node = b * 8 + ni;
        float acc = 0.f;
        if (node < N_NODES) {
            acc = bb;
            #pragma unroll
            for (int k = 0; k < 11; ++k) acc += x[node * 11 + k] * w[k];
            acc = fmaxf(acc, 0.f);
        }
        hA[(size_t)node * D + t] = f2bf(acc);
    }
}

// ---- k2: deg_inv_sqrt + per-256-chunk inclusive scan + last-block bsum scan ----
__global__ __launch_bounds__(256) void k2_kernel(const int* __restrict__ cnt,
                                                 float* __restrict__ dis,
                                                 int* __restrict__ locs,
                                                 int* __restrict__ bsum,
                                                 int* __restrict__ done) {
    __shared__ int ws[4];
    __shared__ int amLast;
    int t = threadIdx.x, lane = t & 63, wv = t >> 6;
    int i = blockIdx.x * 256 + t;
    int v = (i < N_NODES) ? cnt[i] : 0;
    if (i < N_NODES) dis[i] = rsqrtf((float)v);        // deg >= 1 (self-loop)
    int s = v;
    #pragma unroll
    for (int d = 1; d < 64; d <<= 1) {
        int u = __shfl_up(s, d, 64);
        if (lane >= d) s += u;
    }
    if (lane == 63) ws[wv] = s;
    __syncthreads();
    int off = 0;
    #pragma unroll
    for (int k = 0; k < 4; ++k) if (k < wv) off += ws[k];
    s += off;
    if (i < N_NODES) locs[i] = s;                      // inclusive local scan

    // publish chunk total + elect last block
    if (t == 255) {
        bsum[blockIdx.x] = s;
        __threadfence();
        amLast = (atomicAdd(done, 1) == SCAN_B - 1);
    }
    __syncthreads();
    if (amLast) {
        __threadfence();                               // acquire side
        int vv = 0;
        if (t < SCAN_B)
            vv = __hip_atomic_load(&bsum[t], __ATOMIC_RELAXED, __HIP_MEMORY_SCOPE_AGENT);
        int ss = vv;
        #pragma unroll
        for (int d = 1; d < 64; d <<= 1) {
            int u = __shfl_up(ss, d, 64);
            if (lane >= d) ss += u;
        }
        __syncthreads();                               // ws reuse
        if (lane == 63) ws[wv] = ss;
        __syncthreads();
        int off2 = 0;
        #pragma unroll
        for (int k = 0; k < 4; ++k) if (k < wv) off2 += ws[k];
        ss += off2;
        if (t < SCAN_B) bsum[t] = ss - vv;             // exclusive block offsets
    }
}

// ---- k3: rowptr materialization + CSR fill (esrc only; norm factored) ----
__global__ void k3_kernel(const int* __restrict__ ei, const int* __restrict__ locs,
                          const int* __restrict__ bsum, int* __restrict__ fc,
                          int* __restrict__ rowptr, int* __restrict__ esrc) {
    int tid = blockIdx.x * 256 + threadIdx.x;
    if (tid == 0) rowptr[0] = 0;
    if (tid < N_NODES)
        rowptr[tid + 1] = locs[tid] + bsum[tid >> 8];
    if (tid < N_TOT) {
        int src, dst;
        if (tid < N_EDGES) { src = ei[tid]; dst = ei[N_EDGES + tid]; }
        else               { src = dst = tid - N_EDGES; }
        int base = bsum[dst >> 8] + ((dst & 255) ? locs[dst - 1] : 0);
        int pos = base + atomicAdd(&fc[dst], 1);
        esrc[pos] = src;
    }
}

// ---- GEMM (m97-style): C[MPAD,256] = A @ W, W as Wt[n][k]; 128x128 tile, BK=32 ----
__global__ __launch_bounds__(256) void gemm_kernel(const unsigned short* __restrict__ A,
                                                   const unsigned short* __restrict__ Bt,
                                                   unsigned short* __restrict__ C) {
    __shared__ unsigned short lA[128 * 32];
    __shared__ unsigned short lB[128 * 32];
    int t = threadIdx.x;
    int wv = t >> 6, lane = t & 63;
    int m0 = blockIdx.x * 128;
    int n0 = blockIdx.y * 128;
    int moff = (wv & 1) * 64, noff = (wv >> 1) * 64;
    int q = lane >> 4, r = lane & 15;

    int srow = t >> 2;
    int skof = (t & 3) * 8;

    const unsigned short* Ag0 = A  + (size_t)(m0 + srow) * D + skof;
    const unsigned short* Ag1 = Ag0 + (size_t)64 * D;
    const unsigned short* Bg0 = Bt + (size_t)(n0 + srow) * D + skof;
    const unsigned short* Bg1 = Bg0 + (size_t)64 * D;
    unsigned short* lA0 = lA + t * 8;
    unsigned short* lA1 = lA0 + 64 * 32;
    unsigned short* lB0 = lB + t * 8;
    unsigned short* lB1 = lB0 + 64 * 32;

    f32x4 acc[4][4] = {};
    for (int kk = 0; kk < D; kk += 32) {
        __syncthreads();
        g2lds16(Ag0 + kk, lA0);
        g2lds16(Ag1 + kk, lA1);
        g2lds16(Bg0 + kk, lB0);
        g2lds16(Bg1 + kk, lB1);
        __syncthreads();
        bf16x8 a[4], b[4];
        #pragma unroll
        for (int mt = 0; mt < 4; ++mt)
            a[mt] = *(const bf16x8*)(lA + (moff + mt * 16 + r) * 32 + q * 8);
        #pragma unroll
        for (int nt = 0; nt < 4; ++nt)
            b[nt] = *(const bf16x8*)(lB + (noff + nt * 16 + r) * 32 + q * 8);
        #pragma unroll
        for (int mt = 0; mt < 4; ++mt)
            #pragma unroll
            for (int nt = 0; nt < 4; ++nt)
                acc[mt][nt] = __builtin_amdgcn_mfma_f32_16x16x32_bf16(a[mt], b[nt], acc[mt][nt], 0, 0, 0);
    }
    #pragma unroll
    for (int mt = 0; mt < 4; ++mt)
        #pragma unroll
        for (int nt = 0; nt < 4; ++nt) {
            int col  = n0 + noff + nt * 16 + r;
            int rowb = m0 + moff + mt * 16 + q * 4;
            #pragma unroll
            for (int i = 0; i < 4; ++i)
                C[(size_t)(rowb + i) * D + col] = f2bf(acc[mt][nt][i]);
        }
}

// ---- agg v4: wave per node, 2 edges/trip via half-waves (512B/edge), factored
// norm (dis[src] gathered lane-parallel), 2-deep software-pipelined inner loop ----
__global__ __launch_bounds__(256) void agg_kernel(const unsigned short* __restrict__ hw,
                                                  const int* __restrict__ rowptr,
                                                  const int* __restrict__ esrc,
                                                  const float* __restrict__ dis,
                                                  const float* __restrict__ bias,
                                                  unsigned short* __restrict__ out_bf,
                                                  float* __restrict__ out_f32,
                                                  int mode) {
    int wid  = threadIdx.x >> 6;
    int lane = threadIdx.x & 63;
    int node = blockIdx.x * 4 + wid;
    if (node >= N_NODES) return;
    int s0 = rowptr[node], s1 = rowptr[node + 1];
    int half = lane >> 5, hl = lane & 31;

    float acc[8] = {};
    for (int base = s0; base < s1; base += 64) {   // one trip in practice (deg << 64)
        int ec = s1 - base; if (ec > 64) ec = 64;
        int srcl = 0; float dsl = 0.f;
        if (lane < ec) { srcl = esrc[base + lane]; dsl = dis[srcl]; }
        int it = (ec + 1) >> 1;
        // pipeline: trip 0 load up front
        int   sc = __shfl(srcl, half, 64);         // lanes >= ec carry dsl = 0
        float nc = __shfl(dsl,  half, 64);
        u16x8 hc = *(const u16x8*)(hw + (size_t)sc * D + hl * 8);
        for (int i = 1; i < it; ++i) {
            int   e  = 2 * i + half;
            int   sn = __shfl(srcl, e, 64);
            float nn = __shfl(dsl,  e, 64);
            u16x8 hn = *(const u16x8*)(hw + (size_t)sn * D + hl * 8);
            #pragma unroll
            for (int k = 0; k < 8; ++k) acc[k] += nc * bf2f(hc[k]);
            nc = nn; hc = hn;
        }
        #pragma unroll
        for (int k = 0; k < 8; ++k) acc[k] += nc * bf2f(hc[k]);
    }
    #pragma unroll
    for (int k = 0; k < 8; ++k) acc[k] += __shfl_xor(acc[k], 32, 64);

    if (lane < 32) {
        int c = hl * 8;
        float dn = dis[node];
        float4 bv0 = *(const float4*)(bias + c);
        float4 bv1 = *(const float4*)(bias + c + 4);
        float v[8];
        v[0] = dn * acc[0] + bv0.x; v[1] = dn * acc[1] + bv0.y;
        v[2] = dn * acc[2] + bv0.z; v[3] = dn * acc[3] + bv0.w;
        v[4] = dn * acc[4] + bv1.x; v[5] = dn * acc[5] + bv1.y;
        v[6] = dn * acc[6] + bv1.z; v[7] = dn * acc[7] + bv1.w;
        if (mode) {
            u16x8 ov;
            #pragma unroll
            for (int k = 0; k < 8; ++k) ov[k] = f2bf(fmaxf(v[k], 0.f));
            *(u16x8*)(out_bf + (size_t)node * D + c) = ov;
        } else {
            float4 o0 = { v[0], v[1], v[2], v[3] };
            float4 o1 = { v[4], v[5], v[6], v[7] };
            *(float4*)(out_f32 + (size_t)node * D + c)     = o0;
            *(float4*)(out_f32 + (size_t)node * D + c + 4) = o1;
        }
    }
}

extern "C" void kernel_launch(void* const* d_in, const int* in_sizes, int n_in,
                              void* d_out, int out_size, void* d_ws, size_t ws_size,
                              hipStream_t stream) {
    const float* x  = (const float*)d_in[0];
    const int*   ei = (const int*)d_in[1];
    const float* We = (const float*)d_in[2];
    const float* be = (const float*)d_in[3];
    const float* W1 = (const float*)d_in[4];
    const float* b1 = (const float*)d_in[5];
    const float* W2 = (const float*)d_in[6];
    const float* b2 = (const float*)d_in[7];
    float* out = (float*)d_out;

    char* w = (char*)d_ws;
    auto alloc = [&](size_t bytes) {
        char* p = w;
        w += (bytes + 255) & ~(size_t)255;
        return p;
    };
    // cnt, fc, done contiguous -> single memset covers all three
    int*            cnt    = (int*)alloc((size_t)N_NODES * 4);
    int*            fc     = (int*)alloc((size_t)N_NODES * 4);
    int*            done   = (int*)alloc(4);
    size_t zero_span = (size_t)((char*)(done + 64) - (char*)cnt);
    int*            rowptr = (int*)alloc((size_t)(N_NODES + 1) * 4);
    int*            locs   = (int*)alloc((size_t)N_NODES * 4);
    int*            bsum   = (int*)alloc((size_t)SCAN_B * 4);
    float*          dis    = (float*)alloc((size_t)N_NODES * 4);
    int*            esrc   = (int*)alloc((size_t)N_TOT * 4);
    unsigned short* Wt1    = (unsigned short*)alloc((size_t)D * D * 2);
    unsigned short* Wt2    = (unsigned short*)alloc((size_t)D * D * 2);
    unsigned short* hA     = (unsigned short*)alloc((size_t)MPAD * D * 2);
    unsigned short* hW     = (unsigned short*)alloc((size_t)MPAD * D * 2);

    hipMemsetAsync(cnt, 0, zero_span, stream);
    k1_kernel<<<MPAD / 8, 256, 0, stream>>>(x, ei, We, be, W1, W2, cnt, Wt1, Wt2, hA);
    k2_kernel<<<SCAN_B, 256, 0, stream>>>(cnt, dis, locs, bsum, done);
    k3_kernel<<<(N_TOT + 255) / 256, 256, 0, stream>>>(ei, locs, bsum, fc, rowptr, esrc);

    dim3 ggrid(MPAD / 128, 2);
    gemm_kernel<<<ggrid, 256, 0, stream>>>(hA, Wt1, hW);
    agg_kernel<<<(N_NODES + 3) / 4, 256, 0, stream>>>(hW, rowptr, esrc, dis, b1, hA, nullptr, 1);

    gemm_kernel<<<ggrid, 256, 0, stream>>>(hA, Wt2, hW);
    agg_kernel<<<(N_NODES + 3) / 4, 256, 0, stream>>>(hW, rowptr, esrc, dis, b2, nullptr, out, 0);
}

// Round 9
// 234.204 us; speedup vs baseline: 1.5935x; 1.0078x over previous
//
#include <hip/hip_runtime.h>

#define N_NODES 50000
#define N_EDGES 300000
#define N_TOT   350000   // edges + self-loops
#define D       256
#define MPAD    50048    // N_NODES padded to multiple of 128 for GEMM
#define SCAN_B  196      // ceil(50000/256)

typedef __attribute__((ext_vector_type(8))) short bf16x8;
typedef __attribute__((ext_vector_type(4))) float f32x4;
typedef __attribute__((ext_vector_type(8))) unsigned short u16x8;

__device__ __forceinline__ float bf2f(unsigned short b) {
    union { unsigned u; float f; } v; v.u = ((unsigned)b) << 16; return v.f;
}
__device__ __forceinline__ unsigned short f2bf(float f) {
    union { float f; unsigned u; } v; v.f = f;
    unsigned u = v.u;
    unsigned r = (u + 0x7FFFu + ((u >> 16) & 1u)) >> 16;   // round-nearest-even
    return (unsigned short)r;
}
__device__ __forceinline__ void g2lds16(const unsigned short* g, unsigned short* l) {
    __builtin_amdgcn_global_load_lds(
        (const __attribute__((address_space(1))) void*)g,
        (__attribute__((address_space(3))) void*)l, 16, 0, 0);
}

// ---- k1: hist + W-transpose + embed, all independent, grid = MPAD/8 = 6256 ----
__global__ __launch_bounds__(256) void k1_kernel(
        const float* __restrict__ x, const int* __restrict__ ei,
        const float* __restrict__ We, const float* __restrict__ be,
        const float* __restrict__ W1, const float* __restrict__ W2,
        int* __restrict__ cnt,
        unsigned short* __restrict__ Wt1, unsigned short* __restrict__ Wt2,
        unsigned short* __restrict__ hA) {
    int t = threadIdx.x, b = blockIdx.x;
    int tid = b * 256 + t;

    // histogram over dst (cnt pre-zeroed by memset)
    if (tid < N_TOT) {
        int dst = (tid < N_EDGES) ? ei[N_EDGES + tid] : (tid - N_EDGES);
        atomicAdd(&cnt[dst], 1);
    }
    // transpose + cast weights (first 512 blocks, 1 elem/thread)
    if (tid < 2 * D * D) {
        int wsel = tid >> 16, rem = tid & 65535;
        int tt = rem >> 8, bb = rem & 255;             // coalesced over bb
        const float* W = wsel ? W2 : W1;
        unsigned short* Wt = wsel ? Wt2 : Wt1;
        Wt[bb * D + tt] = f2bf(W[tt * D + bb]);
    }
    // embed: block b -> nodes b*8 .. b*8+7 (pad rows get 0)
    float w[11];
    #pragma unroll
    for (int k = 0; k < 11; ++k) w[k] = We[k * D + t];
    float bb = be[t];
    #pragma unroll
    for (int ni = 0; ni < 8; ++ni) {
        int node = b * 8 + ni;
        float acc = 0.f;
        if (node < N_NODES) {
            acc = bb;
            #pragma unroll
            for (int k = 0; k < 11; ++k) acc += x[node * 11 + k] * w[k];
            acc = fmaxf(acc, 0.f);
        }
        hA[(size_t)node * D + t] = f2bf(acc);
    }
}

// ---- k3: rowptr materialization + CSR fill (esrc + enorm) ----
__global__ void k3_kernel(const int* __restrict__ ei, const int* __restrict__ locs,
                          const int* __restrict__ bsum, const float* __restrict__ dis,
                          int* __restrict__ fc, int* __restrict__ rowptr,
                          int* __restrict__ esrc, float* __restrict__ enorm) {
    int tid = blockIdx.x * 256 + threadIdx.x;
    if (tid == 0) rowptr[0] = 0;
    if (tid < N_NODES)
        rowptr[tid + 1] = locs[tid] + bsum[tid >> 8];
    if (tid < N_TOT) {
        int src, dst;
        if (tid < N_EDGES) { src = ei[tid]; dst = ei[N_EDGES + tid]; }
        else               { src = dst = tid - N_EDGES; }
        int base = bsum[dst >> 8] + ((dst & 255) ? locs[dst - 1] : 0);
        int pos = base + atomicAdd(&fc[dst], 1);
        esrc[pos]  = src;
        enorm[pos] = dis[src] * dis[dst];
    }
}

// ---- GEMM (m97-style) + optional k2 side-job in blocks (x<196, y==0):
//      deg_inv_sqrt + per-chunk scan + elected last-block bsum scan ----
__global__ __launch_bounds__(256) void gemm_kernel(const unsigned short* __restrict__ A,
                                                   const unsigned short* __restrict__ Bt,
                                                   unsigned short* __restrict__ C,
                                                   const int* __restrict__ cnt,
                                                   float* __restrict__ dis,
                                                   int* __restrict__ locs,
                                                   int* __restrict__ bsum,
                                                   int* __restrict__ done) {
    __shared__ unsigned short lA[128 * 32];
    __shared__ unsigned short lB[128 * 32];
    __shared__ int ws[4];
    __shared__ int amLast;
    int t = threadIdx.x;

    // ---- side job: k2 scan (only when cnt != nullptr) ----
    if (cnt && blockIdx.y == 0 && blockIdx.x < SCAN_B) {
        int lane = t & 63, wv4 = t >> 6;
        int i = blockIdx.x * 256 + t;
        int v = (i < N_NODES) ? cnt[i] : 0;
        if (i < N_NODES) dis[i] = rsqrtf((float)v);    // deg >= 1 (self-loop)
        int s = v;
        #pragma unroll
        for (int d = 1; d < 64; d <<= 1) {
            int u = __shfl_up(s, d, 64);
            if (lane >= d) s += u;
        }
        if (lane == 63) ws[wv4] = s;
        __syncthreads();
        int off = 0;
        #pragma unroll
        for (int k = 0; k < 4; ++k) if (k < wv4) off += ws[k];
        s += off;
        if (i < N_NODES) locs[i] = s;                  // inclusive local scan
        if (t == 255) {
            bsum[blockIdx.x] = s;
            __threadfence();
            amLast = (atomicAdd(done, 1) == SCAN_B - 1);
        }
        __syncthreads();
        if (amLast) {
            __threadfence();
            int vv = 0;
            if (t < SCAN_B)
                vv = __hip_atomic_load(&bsum[t], __ATOMIC_RELAXED, __HIP_MEMORY_SCOPE_AGENT);
            int ss = vv;
            #pragma unroll
            for (int d = 1; d < 64; d <<= 1) {
                int u = __shfl_up(ss, d, 64);
                if (lane >= d) ss += u;
            }
            __syncthreads();                           // ws reuse
            if (lane == 63) ws[wv4] = ss;
            __syncthreads();
            int off2 = 0;
            #pragma unroll
            for (int k = 0; k < 4; ++k) if (k < wv4) off2 += ws[k];
            ss += off2;
            if (t < SCAN_B) bsum[t] = ss - vv;         // exclusive block offsets
        }
        __syncthreads();
    }

    // ---- GEMM body ----
    int wv = t >> 6, lane = t & 63;
    int m0 = blockIdx.x * 128;
    int n0 = blockIdx.y * 128;
    int moff = (wv & 1) * 64, noff = (wv >> 1) * 64;
    int q = lane >> 4, r = lane & 15;

    int srow = t >> 2;
    int skof = (t & 3) * 8;

    const unsigned short* Ag0 = A  + (size_t)(m0 + srow) * D + skof;
    const unsigned short* Ag1 = Ag0 + (size_t)64 * D;
    const unsigned short* Bg0 = Bt + (size_t)(n0 + srow) * D + skof;
    const unsigned short* Bg1 = Bg0 + (size_t)64 * D;
    unsigned short* lA0 = lA + t * 8;
    unsigned short* lA1 = lA0 + 64 * 32;
    unsigned short* lB0 = lB + t * 8;
    unsigned short* lB1 = lB0 + 64 * 32;

    f32x4 acc[4][4] = {};
    for (int kk = 0; kk < D; kk += 32) {
        __syncthreads();
        g2lds16(Ag0 + kk, lA0);
        g2lds16(Ag1 + kk, lA1);
        g2lds16(Bg0 + kk, lB0);
        g2lds16(Bg1 + kk, lB1);
        __syncthreads();
        bf16x8 a[4], b[4];
        #pragma unroll
        for (int mt = 0; mt < 4; ++mt)
            a[mt] = *(const bf16x8*)(lA + (moff + mt * 16 + r) * 32 + q * 8);
        #pragma unroll
        for (int nt = 0; nt < 4; ++nt)
            b[nt] = *(const bf16x8*)(lB + (noff + nt * 16 + r) * 32 + q * 8);
        #pragma unroll
        for (int mt = 0; mt < 4; ++mt)
            #pragma unroll
            for (int nt = 0; nt < 4; ++nt)
                acc[mt][nt] = __builtin_amdgcn_mfma_f32_16x16x32_bf16(a[mt], b[nt], acc[mt][nt], 0, 0, 0);
    }
    #pragma unroll
    for (int mt = 0; mt < 4; ++mt)
        #pragma unroll
        for (int nt = 0; nt < 4; ++nt) {
            int col  = n0 + noff + nt * 16 + r;
            int rowb = m0 + moff + mt * 16 + q * 4;
            #pragma unroll
            for (int i = 0; i < 4; ++i)
                C[(size_t)(rowb + i) * D + col] = f2bf(acc[mt][nt][i]);
        }
}

// ---- agg v5: wave per node, 2 edges/trip via half-waves (512B/edge),
//      materialized enorm (contiguous prefetch), 2-deep software pipeline ----
__global__ __launch_bounds__(256) void agg_kernel(const unsigned short* __restrict__ hw,
                                                  const int* __restrict__ rowptr,
                                                  const int* __restrict__ esrc,
                                                  const float* __restrict__ enorm,
                                                  const float* __restrict__ bias,
                                                  unsigned short* __restrict__ out_bf,
                                                  float* __restrict__ out_f32,
                                                  int mode) {
    int wid  = threadIdx.x >> 6;
    int lane = threadIdx.x & 63;
    int node = blockIdx.x * 4 + wid;
    if (node >= N_NODES) return;
    int s0 = rowptr[node], s1 = rowptr[node + 1];
    int half = lane >> 5, hl = lane & 31;

    float acc[8] = {};
    for (int base = s0; base < s1; base += 64) {   // one trip in practice (deg << 64)
        int ec = s1 - base; if (ec > 64) ec = 64;
        int srcl = 0; float nml = 0.f;
        if (lane < ec) { srcl = esrc[base + lane]; nml = enorm[base + lane]; }
        int it = (ec + 1) >> 1;
        // pipeline: trip 0 load up front
        int   sc = __shfl(srcl, half, 64);         // lanes >= ec carry nml = 0
        float nc = __shfl(nml,  half, 64);
        u16x8 hc = *(const u16x8*)(hw + (size_t)sc * D + hl * 8);
        for (int i = 1; i < it; ++i) {
            int   e  = 2 * i + half;
            int   sn = __shfl(srcl, e, 64);
            float nn = __shfl(nml,  e, 64);
            u16x8 hn = *(const u16x8*)(hw + (size_t)sn * D + hl * 8);
            #pragma unroll
            for (int k = 0; k < 8; ++k) acc[k] += nc * bf2f(hc[k]);
            nc = nn; hc = hn;
        }
        #pragma unroll
        for (int k = 0; k < 8; ++k) acc[k] += nc * bf2f(hc[k]);
    }
    #pragma unroll
    for (int k = 0; k < 8; ++k) acc[k] += __shfl_xor(acc[k], 32, 64);

    if (lane < 32) {
        int c = hl * 8;
        float4 bv0 = *(const float4*)(bias + c);
        float4 bv1 = *(const float4*)(bias + c + 4);
        float v[8];
        v[0] = acc[0] + bv0.x; v[1] = acc[1] + bv0.y;
        v[2] = acc[2] + bv0.z; v[3] = acc[3] + bv0.w;
        v[4] = acc[4] + bv1.x; v[5] = acc[5] + bv1.y;
        v[6] = acc[6] + bv1.z; v[7] = acc[7] + bv1.w;
        if (mode) {
            u16x8 ov;
            #pragma unroll
            for (int k = 0; k < 8; ++k) ov[k] = f2bf(fmaxf(v[k], 0.f));
            *(u16x8*)(out_bf + (size_t)node * D + c) = ov;
        } else {
            float4 o0 = { v[0], v[1], v[2], v[3] };
            float4 o1 = { v[4], v[5], v[6], v[7] };
            *(float4*)(out_f32 + (size_t)node * D + c)     = o0;
            *(float4*)(out_f32 + (size_t)node * D + c + 4) = o1;
        }
    }
}

extern "C" void kernel_launch(void* const* d_in, const int* in_sizes, int n_in,
                              void* d_out, int out_size, void* d_ws, size_t ws_size,
                              hipStream_t stream) {
    const float* x  = (const float*)d_in[0];
    const int*   ei = (const int*)d_in[1];
    const float* We = (const float*)d_in[2];
    const float* be = (const float*)d_in[3];
    const float* W1 = (const float*)d_in[4];
    const float* b1 = (const float*)d_in[5];
    const float* W2 = (const float*)d_in[6];
    const float* b2 = (const float*)d_in[7];
    float* out = (float*)d_out;

    char* w = (char*)d_ws;
    auto alloc = [&](size_t bytes) {
        char* p = w;
        w += (bytes + 255) & ~(size_t)255;
        return p;
    };
    // cnt, fc, done contiguous -> single memset covers all three
    int*            cnt    = (int*)alloc((size_t)N_NODES * 4);
    int*            fc     = (int*)alloc((size_t)N_NODES * 4);
    int*            done   = (int*)alloc(4);
    size_t zero_span = (size_t)((char*)(done + 64) - (char*)cnt);
    int*            rowptr = (int*)alloc((size_t)(N_NODES + 1) * 4);
    int*            locs   = (int*)alloc((size_t)N_NODES * 4);
    int*            bsum   = (int*)alloc((size_t)SCAN_B * 4);
    float*          dis    = (float*)alloc((size_t)N_NODES * 4);
    int*            esrc   = (int*)alloc((size_t)N_TOT * 4);
    float*          enorm  = (float*)alloc((size_t)N_TOT * 4);
    unsigned short* Wt1    = (unsigned short*)alloc((size_t)D * D * 2);
    unsigned short* Wt2    = (unsigned short*)alloc((size_t)D * D * 2);
    unsigned short* hA     = (unsigned short*)alloc((size_t)MPAD * D * 2);
    unsigned short* hW     = (unsigned short*)alloc((size_t)MPAD * D * 2);

    hipMemsetAsync(cnt, 0, zero_span, stream);
    k1_kernel<<<MPAD / 8, 256, 0, stream>>>(x, ei, We, be, W1, W2, cnt, Wt1, Wt2, hA);

    dim3 ggrid(MPAD / 128, 2);
    // gemm1 carries the k2 scan side-job (needs only k1's cnt)
    gemm_kernel<<<ggrid, 256, 0, stream>>>(hA, Wt1, hW, cnt, dis, locs, bsum, done);
    k3_kernel<<<(N_TOT + 255) / 256, 256, 0, stream>>>(ei, locs, bsum, dis, fc,
                                                       rowptr, esrc, enorm);
    agg_kernel<<<(N_NODES + 3) / 4, 256, 0, stream>>>(hW, rowptr, esrc, enorm, b1,
                                                      hA, nullptr, 1);

    gemm_kernel<<<ggrid, 256, 0, stream>>>(hA, Wt2, hW, nullptr, nullptr, nullptr,
                                           nullptr, nullptr);
    agg_kernel<<<(N_NODES + 3) / 4, 256, 0, stream>>>(hW, rowptr, esrc, enorm, b2,
                                                      nullptr, out, 0);
}

// Round 10
// 231.166 us; speedup vs baseline: 1.6145x; 1.0131x over previous
//
#include <hip/hip_runtime.h>

#define N_NODES 50000
#define N_EDGES 300000
#define N_TOT   350000   // edges + self-loops
#define D       256
#define MPAD    50048    // N_NODES padded to multiple of 128 for GEMM
#define SCAN_B  196      // ceil(50000/256)

typedef __attribute__((ext_vector_type(8))) short bf16x8;
typedef __attribute__((ext_vector_type(4))) float f32x4;
typedef __attribute__((ext_vector_type(8))) unsigned short u16x8;

__device__ __forceinline__ float bf2f(unsigned short b) {
    union { unsigned u; float f; } v; v.u = ((unsigned)b) << 16; return v.f;
}
__device__ __forceinline__ unsigned short f2bf(float f) {
    union { float f; unsigned u; } v; v.f = f;
    unsigned u = v.u;
    unsigned r = (u + 0x7FFFu + ((u >> 16) & 1u)) >> 16;   // round-nearest-even
    return (unsigned short)r;
}
__device__ __forceinline__ void g2lds16(const unsigned short* g, unsigned short* l) {
    __builtin_amdgcn_global_load_lds(
        (const __attribute__((address_space(1))) void*)g,
        (__attribute__((address_space(3))) void*)l, 16, 0, 0);
}

// ---- k1: hist + W-transpose + embed, all independent, grid = MPAD/8 = 6256 ----
__global__ __launch_bounds__(256) void k1_kernel(
        const float* __restrict__ x, const int* __restrict__ ei,
        const float* __restrict__ We, const float* __restrict__ be,
        const float* __restrict__ W1, const float* __restrict__ W2,
        int* __restrict__ cnt,
        unsigned short* __restrict__ Wt1, unsigned short* __restrict__ Wt2,
        unsigned short* __restrict__ hA) {
    int t = threadIdx.x, b = blockIdx.x;
    int tid = b * 256 + t;

    // histogram over dst (cnt pre-zeroed by memset)
    if (tid < N_TOT) {
        int dst = (tid < N_EDGES) ? ei[N_EDGES + tid] : (tid - N_EDGES);
        atomicAdd(&cnt[dst], 1);
    }
    // transpose + cast weights (first 512 blocks, 1 elem/thread)
    if (tid < 2 * D * D) {
        int wsel = tid >> 16, rem = tid & 65535;
        int tt = rem >> 8, bb = rem & 255;             // coalesced over bb
        const float* W = wsel ? W2 : W1;
        unsigned short* Wt = wsel ? Wt2 : Wt1;
        Wt[bb * D + tt] = f2bf(W[tt * D + bb]);
    }
    // embed: block b -> nodes b*8 .. b*8+7 (pad rows get 0)
    float w[11];
    #pragma unroll
    for (int k = 0; k < 11; ++k) w[k] = We[k * D + t];
    float bb = be[t];
    #pragma unroll
    for (int ni = 0; ni < 8; ++ni) {
        int node = b * 8 + ni;
        float acc = 0.f;
        if (node < N_NODES) {
            acc = bb;
            #pragma unroll
            for (int k = 0; k < 11; ++k) acc += x[node * 11 + k] * w[k];
            acc = fmaxf(acc, 0.f);
        }
        hA[(size_t)node * D + t] = f2bf(acc);
    }
}

// ---- k3: rowptr materialization + CSR fill (esrc + enorm) ----
__global__ void k3_kernel(const int* __restrict__ ei, const int* __restrict__ locs,
                          const int* __restrict__ bsum, const float* __restrict__ dis,
                          int* __restrict__ fc, int* __restrict__ rowptr,
                          int* __restrict__ esrc, float* __restrict__ enorm) {
    int tid = blockIdx.x * 256 + threadIdx.x;
    if (tid == 0) rowptr[0] = 0;
    if (tid < N_NODES)
        rowptr[tid + 1] = locs[tid] + bsum[tid >> 8];
    if (tid < N_TOT) {
        int src, dst;
        if (tid < N_EDGES) { src = ei[tid]; dst = ei[N_EDGES + tid]; }
        else               { src = dst = tid - N_EDGES; }
        int base = bsum[dst >> 8] + ((dst & 255) ? locs[dst - 1] : 0);
        int pos = base + atomicAdd(&fc[dst], 1);
        esrc[pos]  = src;
        enorm[pos] = dis[src] * dis[dst];
    }
}

// ---- GEMM (m97-style) + optional k2 side-job in blocks (x<196, y==0) ----
__global__ __launch_bounds__(256) void gemm_kernel(const unsigned short* __restrict__ A,
                                                   const unsigned short* __restrict__ Bt,
                                                   unsigned short* __restrict__ C,
                                                   const int* __restrict__ cnt,
                                                   float* __restrict__ dis,
                                                   int* __restrict__ locs,
                                                   int* __restrict__ bsum,
                                                   int* __restrict__ done) {
    __shared__ unsigned short lA[128 * 32];
    __shared__ unsigned short lB[128 * 32];
    __shared__ int ws[4];
    __shared__ int amLast;
    int t = threadIdx.x;

    // ---- side job: k2 scan (only when cnt != nullptr) ----
    if (cnt && blockIdx.y == 0 && blockIdx.x < SCAN_B) {
        int lane = t & 63, wv4 = t >> 6;
        int i = blockIdx.x * 256 + t;
        int v = (i < N_NODES) ? cnt[i] : 0;
        if (i < N_NODES) dis[i] = rsqrtf((float)v);    // deg >= 1 (self-loop)
        int s = v;
        #pragma unroll
        for (int d = 1; d < 64; d <<= 1) {
            int u = __shfl_up(s, d, 64);
            if (lane >= d) s += u;
        }
        if (lane == 63) ws[wv4] = s;
        __syncthreads();
        int off = 0;
        #pragma unroll
        for (int k = 0; k < 4; ++k) if (k < wv4) off += ws[k];
        s += off;
        if (i < N_NODES) locs[i] = s;                  // inclusive local scan
        if (t == 255) {
            bsum[blockIdx.x] = s;
            __threadfence();
            amLast = (atomicAdd(done, 1) == SCAN_B - 1);
        }
        __syncthreads();
        if (amLast) {
            __threadfence();
            int vv = 0;
            if (t < SCAN_B)
                vv = __hip_atomic_load(&bsum[t], __ATOMIC_RELAXED, __HIP_MEMORY_SCOPE_AGENT);
            int ss = vv;
            #pragma unroll
            for (int d = 1; d < 64; d <<= 1) {
                int u = __shfl_up(ss, d, 64);
                if (lane >= d) ss += u;
            }
            __syncthreads();                           // ws reuse
            if (lane == 63) ws[wv4] = ss;
            __syncthreads();
            int off2 = 0;
            #pragma unroll
            for (int k = 0; k < 4; ++k) if (k < wv4) off2 += ws[k];
            ss += off2;
            if (t < SCAN_B) bsum[t] = ss - vv;         // exclusive block offsets
        }
        __syncthreads();
    }

    // ---- GEMM body ----
    int wv = t >> 6, lane = t & 63;
    int m0 = blockIdx.x * 128;
    int n0 = blockIdx.y * 128;
    int moff = (wv & 1) * 64, noff = (wv >> 1) * 64;
    int q = lane >> 4, r = lane & 15;

    int srow = t >> 2;
    int skof = (t & 3) * 8;

    const unsigned short* Ag0 = A  + (size_t)(m0 + srow) * D + skof;
    const unsigned short* Ag1 = Ag0 + (size_t)64 * D;
    const unsigned short* Bg0 = Bt + (size_t)(n0 + srow) * D + skof;
    const unsigned short* Bg1 = Bg0 + (size_t)64 * D;
    unsigned short* lA0 = lA + t * 8;
    unsigned short* lA1 = lA0 + 64 * 32;
    unsigned short* lB0 = lB + t * 8;
    unsigned short* lB1 = lB0 + 64 * 32;

    f32x4 acc[4][4] = {};
    for (int kk = 0; kk < D; kk += 32) {
        __syncthreads();
        g2lds16(Ag0 + kk, lA0);
        g2lds16(Ag1 + kk, lA1);
        g2lds16(Bg0 + kk, lB0);
        g2lds16(Bg1 + kk, lB1);
        __syncthreads();
        bf16x8 a[4], b[4];
        #pragma unroll
        for (int mt = 0; mt < 4; ++mt)
            a[mt] = *(const bf16x8*)(lA + (moff + mt * 16 + r) * 32 + q * 8);
        #pragma unroll
        for (int nt = 0; nt < 4; ++nt)
            b[nt] = *(const bf16x8*)(lB + (noff + nt * 16 + r) * 32 + q * 8);
        #pragma unroll
        for (int mt = 0; mt < 4; ++mt)
            #pragma unroll
            for (int nt = 0; nt < 4; ++nt)
                acc[mt][nt] = __builtin_amdgcn_mfma_f32_16x16x32_bf16(a[mt], b[nt], acc[mt][nt], 0, 0, 0);
    }
    #pragma unroll
    for (int mt = 0; mt < 4; ++mt)
        #pragma unroll
        for (int nt = 0; nt < 4; ++nt) {
            int col  = n0 + noff + nt * 16 + r;
            int rowb = m0 + moff + mt * 16 + q * 4;
            #pragma unroll
            for (int i = 0; i < 4; ++i)
                C[(size_t)(rowb + i) * D + col] = f2bf(acc[mt][nt][i]);
        }
}

// ---- agg v6: wave per node, 2 edges/trip via half-waves (512B/edge), chunks of
// 2 trips (4 rows in flight before first consume); enorm=0 neutralizes over-issue ----
__global__ __launch_bounds__(256) void agg_kernel(const unsigned short* __restrict__ hw,
                                                  const int* __restrict__ rowptr,
                                                  const int* __restrict__ esrc,
                                                  const float* __restrict__ enorm,
                                                  const float* __restrict__ bias,
                                                  unsigned short* __restrict__ out_bf,
                                                  float* __restrict__ out_f32,
                                                  int mode) {
    int wid  = threadIdx.x >> 6;
    int lane = threadIdx.x & 63;
    int node = blockIdx.x * 4 + wid;
    if (node >= N_NODES) return;
    int s0 = rowptr[node], s1 = rowptr[node + 1];
    int half = lane >> 5, hl = lane & 31;

    float acc[8] = {};
    for (int base = s0; base < s1; base += 64) {   // one trip in practice (deg << 64)
        int ec = s1 - base; if (ec > 64) ec = 64;
        int srcl = 0; float nml = 0.f;
        if (lane < ec) { srcl = esrc[base + lane]; nml = enorm[base + lane]; }
        int it = (ec + 1) >> 1;                    // #trips (2 edges each)
        for (int i = 0; i < it; i += 2) {          // chunk = 2 trips = 4 rows in flight
            int   e0 = (2 * i + half) & 63;
            int   e1 = (2 * i + 2 + half) & 63;
            int   sa = __shfl(srcl, e0, 64);
            float na = __shfl(nml,  e0, 64);
            int   sb = __shfl(srcl, e1, 64);
            float nb = __shfl(nml,  e1, 64);       // nb = 0 when trip i+1 is past end
            u16x8 ha = *(const u16x8*)(hw + (size_t)sa * D + hl * 8);
            u16x8 hb = *(const u16x8*)(hw + (size_t)sb * D + hl * 8);
            #pragma unroll
            for (int k = 0; k < 8; ++k) acc[k] += na * bf2f(ha[k]);
            #pragma unroll
            for (int k = 0; k < 8; ++k) acc[k] += nb * bf2f(hb[k]);
        }
    }
    #pragma unroll
    for (int k = 0; k < 8; ++k) acc[k] += __shfl_xor(acc[k], 32, 64);

    if (lane < 32) {
        int c = hl * 8;
        float4 bv0 = *(const float4*)(bias + c);
        float4 bv1 = *(const float4*)(bias + c + 4);
        float v[8];
        v[0] = acc[0] + bv0.x; v[1] = acc[1] + bv0.y;
        v[2] = acc[2] + bv0.z; v[3] = acc[3] + bv0.w;
        v[4] = acc[4] + bv1.x; v[5] = acc[5] + bv1.y;
        v[6] = acc[6] + bv1.z; v[7] = acc[7] + bv1.w;
        if (mode) {
            u16x8 ov;
            #pragma unroll
            for (int k = 0; k < 8; ++k) ov[k] = f2bf(fmaxf(v[k], 0.f));
            *(u16x8*)(out_bf + (size_t)node * D + c) = ov;
        } else {
            float4 o0 = { v[0], v[1], v[2], v[3] };
            float4 o1 = { v[4], v[5], v[6], v[7] };
            *(float4*)(out_f32 + (size_t)node * D + c)     = o0;
            *(float4*)(out_f32 + (size_t)node * D + c + 4) = o1;
        }
    }
}

extern "C" void kernel_launch(void* const* d_in, const int* in_sizes, int n_in,
                              void* d_out, int out_size, void* d_ws, size_t ws_size,
                              hipStream_t stream) {
    const float* x  = (const float*)d_in[0];
    const int*   ei = (const int*)d_in[1];
    const float* We = (const float*)d_in[2];
    const float* be = (const float*)d_in[3];
    const float* W1 = (const float*)d_in[4];
    const float* b1 = (const float*)d_in[5];
    const float* W2 = (const float*)d_in[6];
    const float* b2 = (const float*)d_in[7];
    float* out = (float*)d_out;

    char* w = (char*)d_ws;
    auto alloc = [&](size_t bytes) {
        char* p = w;
        w += (bytes + 255) & ~(size_t)255;
        return p;
    };
    // cnt, fc, done contiguous -> single memset covers all three
    int*            cnt    = (int*)alloc((size_t)N_NODES * 4);
    int*            fc     = (int*)alloc((size_t)N_NODES * 4);
    int*            done   = (int*)alloc(4);
    size_t zero_span = (size_t)((char*)(done + 64) - (char*)cnt);
    int*            rowptr = (int*)alloc((size_t)(N_NODES + 1) * 4);
    int*            locs   = (int*)alloc((size_t)N_NODES * 4);
    int*            bsum   = (int*)alloc((size_t)SCAN_B * 4);
    float*          dis    = (float*)alloc((size_t)N_NODES * 4);
    int*            esrc   = (int*)alloc((size_t)N_TOT * 4);
    float*          enorm  = (float*)alloc((size_t)N_TOT * 4);
    unsigned short* Wt1    = (unsigned short*)alloc((size_t)D * D * 2);
    unsigned short* Wt2    = (unsigned short*)alloc((size_t)D * D * 2);
    unsigned short* hA     = (unsigned short*)alloc((size_t)MPAD * D * 2);
    unsigned short* hW     = (unsigned short*)alloc((size_t)MPAD * D * 2);

    hipMemsetAsync(cnt, 0, zero_span, stream);
    k1_kernel<<<MPAD / 8, 256, 0, stream>>>(x, ei, We, be, W1, W2, cnt, Wt1, Wt2, hA);

    dim3 ggrid(MPAD / 128, 2);
    // gemm1 carries the k2 scan side-job (needs only k1's cnt)
    gemm_kernel<<<ggrid, 256, 0, stream>>>(hA, Wt1, hW, cnt, dis, locs, bsum, done);
    k3_kernel<<<(N_TOT + 255) / 256, 256, 0, stream>>>(ei, locs, bsum, dis, fc,
                                                       rowptr, esrc, enorm);
    agg_kernel<<<(N_NODES + 3) / 4, 256, 0, stream>>>(hW, rowptr, esrc, enorm, b1,
                                                      hA, nullptr, 1);

    gemm_kernel<<<ggrid, 256, 0, stream>>>(hA, Wt2, hW, nullptr, nullptr, nullptr,
                                           nullptr, nullptr);
    agg_kernel<<<(N_NODES + 3) / 4, 256, 0, stream>>>(hW, rowptr, esrc, enorm, b2,
                                                      nullptr, out, 0);
}